// Round 2
// baseline (454.989 us; speedup 1.0000x reference)
//
#include <hip/hip_runtime.h>

typedef __bf16 bhalf;
typedef __bf16 bhalf8 __attribute__((ext_vector_type(8)));
typedef __bf16 bhalf4 __attribute__((ext_vector_type(4)));
typedef float f32x4 __attribute__((ext_vector_type(4)));

typedef __attribute__((address_space(1))) const void* gas_p;
typedef __attribute__((address_space(3))) void* las_p;

#define T_SEQ 2048
#define HIDN  2048
#define NQH   32
#define NKVH  8
#define DH    64
#define NQKV  3072  // (NQ + 2*NKV) * D

// ---------------- elementwise cast fp32 -> bf16 ----------------
__global__ __launch_bounds__(256) void cast_bf16_k(const float* __restrict__ in,
                                                   bhalf* __restrict__ out, int n) {
  int i = (blockIdx.x * 256 + threadIdx.x) * 4;
  if (i + 3 < n) {
    float4 v = *(const float4*)(in + i);
    bhalf4 o;
    o[0] = (bhalf)v.x; o[1] = (bhalf)v.y; o[2] = (bhalf)v.z; o[3] = (bhalf)v.w;
    *(bhalf4*)(out + i) = o;
  }
}

// ---------------- transpose + cast fp32->bf16: out[C][R] = (bf16) in[R][C] ----------------
__global__ __launch_bounds__(256) void transpose_cast_k(const float* __restrict__ in,
                                                        bhalf* __restrict__ out, int R, int C) {
  __shared__ float tile[32][33];
  int bx = blockIdx.x * 32;
  int by = blockIdx.y * 32;
  int tx = threadIdx.x & 31, ty = threadIdx.x >> 5;
#pragma unroll
  for (int p = 0; p < 4; ++p)
    tile[ty + 8 * p][tx] = in[(size_t)(by + ty + 8 * p) * C + bx + tx];
  __syncthreads();
#pragma unroll
  for (int p = 0; p < 4; ++p)
    out[(size_t)(bx + ty + 8 * p) * R + by + tx] = (bhalf)tile[tx][ty + 8 * p];
}

// ---------------- bf16 transpose: out[C][R] = in[R][C] ----------------
__global__ __launch_bounds__(256) void transpose_bf16_k(const bhalf* __restrict__ in,
                                                        bhalf* __restrict__ out, int R, int C) {
  __shared__ bhalf tile[32][33];
  int bx = blockIdx.x * 32;
  int by = blockIdx.y * 32;
  int tx = threadIdx.x & 31, ty = threadIdx.x >> 5;
#pragma unroll
  for (int p = 0; p < 4; ++p)
    tile[ty + 8 * p][tx] = in[(size_t)(by + ty + 8 * p) * C + bx + tx];
  __syncthreads();
#pragma unroll
  for (int p = 0; p < 4; ++p)
    out[(size_t)(bx + ty + 8 * p) * R + by + tx] = tile[tx][ty + 8 * p];
}

// ---------------- bf16 MFMA GEMM: C[M][N] = A[M][K] * Bt[N][K]^T ----------------
// 128x128 block tile, BK=32, 4 waves 2x2, each wave 64x64 (4x4 of 16x16x32).
// Staging via global_load_lds width=16 (m97 pattern): unpadded [128][32] LDS tiles,
// wave-uniform LDS base + lane*16.
__global__ __launch_bounds__(256) void gemm_bf16_k(const bhalf* __restrict__ A,
                                                   const bhalf* __restrict__ Bt,
                                                   float* __restrict__ C, int M, int N, int K) {
  __shared__ __align__(16) bhalf As[128 * 32];
  __shared__ __align__(16) bhalf Bs[128 * 32];
  int tid = threadIdx.x, lane = tid & 63, wv = tid >> 6;
  int bm = blockIdx.y * 128, bn = blockIdx.x * 128;
  int wm = (wv >> 1) * 64, wn = (wv & 1) * 64;
  int m16 = lane & 15, q4 = lane >> 4;
  f32x4 zero4 = {0.f, 0.f, 0.f, 0.f};
  f32x4 acc[4][4];
#pragma unroll
  for (int mi = 0; mi < 4; ++mi)
#pragma unroll
    for (int ni = 0; ni < 4; ++ni) acc[mi][ni] = zero4;

  // per-thread staging source coords (idx = c*256 + tid; row = idx>>2, col = (idx&3)*8)
  int r0 = tid >> 2, c0 = (tid & 3) * 8;
  const bhalf* a0 = A + (size_t)(bm + r0) * K + c0;
  const bhalf* a1 = A + (size_t)(bm + 64 + r0) * K + c0;
  const bhalf* b0 = Bt + (size_t)(bn + r0) * K + c0;
  const bhalf* b1 = Bt + (size_t)(bn + 64 + r0) * K + c0;
  bhalf* lds_a0 = As + wv * 512;          // bytes: wv*1024, lane adds lane*16
  bhalf* lds_a1 = As + (4 + wv) * 512;
  bhalf* lds_b0 = Bs + wv * 512;
  bhalf* lds_b1 = Bs + (4 + wv) * 512;

  for (int k0 = 0; k0 < K; k0 += 32) {
    __builtin_amdgcn_global_load_lds((gas_p)(a0 + k0), (las_p)lds_a0, 16, 0, 0);
    __builtin_amdgcn_global_load_lds((gas_p)(a1 + k0), (las_p)lds_a1, 16, 0, 0);
    __builtin_amdgcn_global_load_lds((gas_p)(b0 + k0), (las_p)lds_b0, 16, 0, 0);
    __builtin_amdgcn_global_load_lds((gas_p)(b1 + k0), (las_p)lds_b1, 16, 0, 0);
    __syncthreads();
    bhalf8 af[4], bfr[4];
#pragma unroll
    for (int mi = 0; mi < 4; ++mi)
      af[mi] = *(const bhalf8*)&As[(wm + mi * 16 + m16) * 32 + q4 * 8];
#pragma unroll
    for (int ni = 0; ni < 4; ++ni)
      bfr[ni] = *(const bhalf8*)&Bs[(wn + ni * 16 + m16) * 32 + q4 * 8];
#pragma unroll
    for (int mi = 0; mi < 4; ++mi)
#pragma unroll
      for (int ni = 0; ni < 4; ++ni)
        acc[mi][ni] = __builtin_amdgcn_mfma_f32_16x16x32_bf16(af[mi], bfr[ni], acc[mi][ni], 0, 0, 0);
    __syncthreads();
  }
  // epilogue: C/D layout col = lane&15, row = (lane>>4)*4 + r
#pragma unroll
  for (int mi = 0; mi < 4; ++mi)
#pragma unroll
    for (int ni = 0; ni < 4; ++ni) {
      size_t base = (size_t)(bm + wm + mi * 16 + q4 * 4) * N + (bn + wn + ni * 16 + m16);
#pragma unroll
      for (int r = 0; r < 4; ++r) C[base + (size_t)r * N] = acc[mi][ni][r];
    }
}

// ---------------- fused RMSNorm + RoPE + split + cast ----------------
__global__ __launch_bounds__(256) void normrope_k(const float* __restrict__ qkv,
                                                  const int* __restrict__ pos,
                                                  const float* __restrict__ qw,
                                                  const float* __restrict__ kw,
                                                  bhalf* __restrict__ qo,
                                                  bhalf* __restrict__ ko,
                                                  bhalf* __restrict__ vo) {
  int wid = blockIdx.x * 4 + (threadIdx.x >> 6);
  int lane = threadIdx.x & 63;
  int t = wid / 48, h = wid - t * 48;
  float x = qkv[(size_t)t * NQKV + h * 64 + lane];
  float o = x;
  if (h < 40) {
    float ss = x * x;
#pragma unroll
    for (int off = 32; off; off >>= 1) ss += __shfl_xor(ss, off);
    float y = x * rsqrtf(ss * (1.0f / 64.0f) + 1e-5f) * ((h < 32) ? qw[lane] : kw[lane]);
    int i = lane & 31;
    float freq = exp2f((float)i * -0.6228615177913804f);
    float ang = (float)pos[t] * freq;
    float c = cosf(ang), s = sinf(ang);
    float partner = __shfl_xor(y, 32);
    o = (lane < 32) ? (y * c - partner * s) : (y * c + partner * s);
  }
  if (h < 32)      qo[(size_t)t * 2048 + h * 64 + lane] = (bhalf)o;
  else if (h < 40) ko[(size_t)t * 512 + (h - 32) * 64 + lane] = (bhalf)o;
  else             vo[(size_t)t * 512 + (h - 40) * 64 + lane] = (bhalf)o;
}

// ---------------- flash attention (causal GQA), fixed-max softmax, no barriers ---------
// grid (T/64, NQ); 4 waves, wave w owns 16 q-rows; s-chunks of 32.
// |score| = |q.k|/8 <= ||q||*||k||/8 = 8 (rmsnorm => ||q||=||k||=8), so a FIXED
// softmax max of 8 is safe: p = exp2(raw*0.125*log2e - 8*log2e) in (0,1].
// K frags + V^T frags load 16B direct from global (L1/L2 served); only the
// P C-layout->A-layout round-trip uses LDS (wave-private, ld=36 => conflict-free).
__global__ __launch_bounds__(256) void attn_k(const bhalf* __restrict__ q,
                                              const bhalf* __restrict__ k,
                                              const bhalf* __restrict__ vt,
                                              bhalf* __restrict__ o) {
  __shared__ __align__(16) bhalf pb[4][16][36];
  int tid = threadIdx.x, lane = tid & 63, w = tid >> 6;
  int h = blockIdx.y, kh = h >> 2;
  int qb = blockIdx.x * 64;
  int m16 = lane & 15, q4 = lane >> 4;

  int trow = qb + w * 16 + m16;
  const bhalf* qp = q + (size_t)trow * 2048 + h * 64;
  bhalf8 qf0 = *(const bhalf8*)(qp + q4 * 8);
  bhalf8 qf1 = *(const bhalf8*)(qp + 32 + q4 * 8);

  f32x4 zero4 = {0.f, 0.f, 0.f, 0.f};
  f32x4 oacc[4];
  float psum[4] = {0.f, 0.f, 0.f, 0.f};
#pragma unroll
  for (int ni = 0; ni < 4; ++ni) oacc[ni] = zero4;

  const float C1 = 0.18033688011112042f;   // 0.125 * log2(e)
  const float C2 = 11.541560327111707f;    // 8 * log2(e)

  int tmax = qb + w * 16 + 15;
  int nch = (tmax >> 5) + 1;
  const bhalf* kbase = k + kh * 64;
  const bhalf* vbase = vt + (size_t)(kh * 64) * 2048;  // [d][t]

  for (int sc = 0; sc < nch; ++sc) {
    int s0 = sc * 32;
    f32x4 sa[2];
#pragma unroll
    for (int st = 0; st < 2; ++st) {
      const bhalf* kp = kbase + (size_t)(s0 + st * 16 + m16) * 512 + q4 * 8;
      bhalf8 kf0 = *(const bhalf8*)kp;
      bhalf8 kf1 = *(const bhalf8*)(kp + 32);
      f32x4 t0 = __builtin_amdgcn_mfma_f32_16x16x32_bf16(qf0, kf0, zero4, 0, 0, 0);
      sa[st] = __builtin_amdgcn_mfma_f32_16x16x32_bf16(qf1, kf1, t0, 0, 0, 0);
    }
#pragma unroll
    for (int r = 0; r < 4; ++r) {
      int tr = qb + w * 16 + q4 * 4 + r;
#pragma unroll
      for (int st = 0; st < 2; ++st) {
        int scol = s0 + st * 16 + m16;
        float pe = (scol <= tr) ? exp2f(sa[st][r] * C1 - C2) : 0.f;
        psum[r] += pe;
        pb[w][q4 * 4 + r][st * 16 + m16] = (bhalf)pe;
      }
    }
    bhalf8 ap = *(const bhalf8*)&pb[w][m16][q4 * 8];
#pragma unroll
    for (int ni = 0; ni < 4; ++ni) {
      bhalf8 bv = *(const bhalf8*)(vbase + (size_t)(ni * 16 + m16) * 2048 + s0 + q4 * 8);
      oacc[ni] = __builtin_amdgcn_mfma_f32_16x16x32_bf16(ap, bv, oacc[ni], 0, 0, 0);
    }
  }
  // row-sum lives split across the 16 m16 lanes of each q4 group: reduce once.
#pragma unroll
  for (int r = 0; r < 4; ++r) {
    float ps = psum[r];
    ps += __shfl_xor(ps, 1);
    ps += __shfl_xor(ps, 2);
    ps += __shfl_xor(ps, 4);
    ps += __shfl_xor(ps, 8);
    psum[r] = ps;
  }
#pragma unroll
  for (int ni = 0; ni < 4; ++ni)
#pragma unroll
    for (int r = 0; r < 4; ++r) {
      int tr = qb + w * 16 + q4 * 4 + r;
      o[(size_t)tr * 2048 + h * 64 + ni * 16 + m16] = (bhalf)(oacc[ni][r] / psum[r]);
    }
}

extern "C" void kernel_launch(void* const* d_in, const int* in_sizes, int n_in,
                              void* d_out, int out_size, void* d_ws, size_t ws_size,
                              hipStream_t stream) {
  const int* positions = (const int*)d_in[0];
  const float* hidden  = (const float*)d_in[1];
  const float* w_qkv   = (const float*)d_in[2];
  const float* w_out   = (const float*)d_in[3];
  const float* q_ln    = (const float*)d_in[4];
  const float* k_ln    = (const float*)d_in[5];
  float* out = (float*)d_out;

  char* wsp = (char*)d_ws;
  bhalf* hid_bf  = (bhalf*)(wsp);                 //  8,388,608 B (dead after gemm1)
  bhalf* wqkvT   = (bhalf*)(wsp + 8388608);       // 12,582,912 B (3072 x 2048)
  bhalf* woutT   = (bhalf*)(wsp + 20971520);      //  8,388,608 B (2048 x 2048)
  float* qkv     = (float*)(wsp + 29360128);      // 25,165,824 B (2048 x 3072 fp32)
  bhalf* q_bf    = (bhalf*)(wsp + 54525952);      //  8,388,608 B
  bhalf* k_bf    = (bhalf*)(wsp + 62914560);      //  2,097,152 B
  bhalf* v_bf    = (bhalf*)(wsp + 65011712);      //  2,097,152 B  (total 64 MiB)
  bhalf* vt_g    = (bhalf*)(wsp);                 // aliases hid_bf (dead by then)
  bhalf* attn_bf = (bhalf*)(wsp + 29360128);      // aliases qkv (dead after normrope)

  cast_bf16_k<<<T_SEQ * HIDN / 1024, 256, 0, stream>>>(hidden, hid_bf, T_SEQ * HIDN);
  transpose_cast_k<<<dim3(NQKV / 32, HIDN / 32), 256, 0, stream>>>(w_qkv, wqkvT, HIDN, NQKV);
  transpose_cast_k<<<dim3(HIDN / 32, HIDN / 32), 256, 0, stream>>>(w_out, woutT, HIDN, HIDN);
  gemm_bf16_k<<<dim3(NQKV / 128, T_SEQ / 128), 256, 0, stream>>>(hid_bf, wqkvT, qkv,
                                                                 T_SEQ, NQKV, HIDN);
  normrope_k<<<T_SEQ * 48 / 4, 256, 0, stream>>>(qkv, positions, q_ln, k_ln, q_bf, k_bf, v_bf);
  transpose_bf16_k<<<dim3(512 / 32, T_SEQ / 32), 256, 0, stream>>>(v_bf, vt_g, T_SEQ, 512);
  attn_k<<<dim3(T_SEQ / 64, NQH), 256, 0, stream>>>(q_bf, k_bf, vt_g, attn_bf);
  gemm_bf16_k<<<dim3(HIDN / 128, T_SEQ / 128), 256, 0, stream>>>(attn_bf, woutT, out,
                                                                 T_SEQ, HIDN, HIDN);
}

// Round 3
// 299.362 us; speedup vs baseline: 1.5199x; 1.5199x over previous
//
#include <hip/hip_runtime.h>

typedef __bf16 bhalf;
typedef __bf16 bhalf8 __attribute__((ext_vector_type(8)));
typedef __bf16 bhalf4 __attribute__((ext_vector_type(4)));
typedef float f32x4 __attribute__((ext_vector_type(4)));

typedef __attribute__((address_space(1))) const void* gas_p;
typedef __attribute__((address_space(3))) void* las_p;

#define T_SEQ 2048
#define HIDN  2048
#define NQH   32
#define NKVH  8
#define DH    64
#define NQKV  3072

// ---------------- elementwise cast fp32 -> bf16 ----------------
__global__ __launch_bounds__(256) void cast_bf16_k(const float* __restrict__ in,
                                                   bhalf* __restrict__ out, int n) {
  int i = (blockIdx.x * 256 + threadIdx.x) * 4;
  if (i + 3 < n) {
    float4 v = *(const float4*)(in + i);
    bhalf4 o;
    o[0] = (bhalf)v.x; o[1] = (bhalf)v.y; o[2] = (bhalf)v.z; o[3] = (bhalf)v.w;
    *(bhalf4*)(out + i) = o;
  }
}

// ---------------- transpose + cast fp32->bf16: out[C][R] = (bf16) in[R][C] ----------------
__global__ __launch_bounds__(256) void transpose_cast_k(const float* __restrict__ in,
                                                        bhalf* __restrict__ out, int R, int C) {
  __shared__ float tile[32][33];
  int bx = blockIdx.x * 32;
  int by = blockIdx.y * 32;
  int tx = threadIdx.x & 31, ty = threadIdx.x >> 5;
#pragma unroll
  for (int p = 0; p < 4; ++p)
    tile[ty + 8 * p][tx] = in[(size_t)(by + ty + 8 * p) * C + bx + tx];
  __syncthreads();
#pragma unroll
  for (int p = 0; p < 4; ++p)
    out[(size_t)(bx + ty + 8 * p) * R + by + tx] = (bhalf)tile[tx][ty + 8 * p];
}

// ---------------- bf16 transpose: out[C][R] = in[R][C] ----------------
__global__ __launch_bounds__(256) void transpose_bf16_k(const bhalf* __restrict__ in,
                                                        bhalf* __restrict__ out, int R, int C) {
  __shared__ bhalf tile[32][33];
  int bx = blockIdx.x * 32;
  int by = blockIdx.y * 32;
  int tx = threadIdx.x & 31, ty = threadIdx.x >> 5;
#pragma unroll
  for (int p = 0; p < 4; ++p)
    tile[ty + 8 * p][tx] = in[(size_t)(by + ty + 8 * p) * C + bx + tx];
  __syncthreads();
#pragma unroll
  for (int p = 0; p < 4; ++p)
    out[(size_t)(bx + ty + 8 * p) * R + by + tx] = tile[tx][ty + 8 * p];
}

// ---------------- bf16 MFMA GEMM: C[M][N] = A[M][K] * Bt[N][K]^T ----------------
// 128x128 tile, BK=32, global_load_lds staging, XOR-swizzled LDS (kills the
// 8-way ds_read_b128 conflicts of the unpadded [128][32] layout).
__global__ __launch_bounds__(256) void gemm_bf16_k(const bhalf* __restrict__ A,
                                                   const bhalf* __restrict__ Bt,
                                                   float* __restrict__ C, int M, int N, int K) {
  __shared__ __align__(16) bhalf As[128 * 32];
  __shared__ __align__(16) bhalf Bs[128 * 32];
  int tid = threadIdx.x, lane = tid & 63, wv = tid >> 6;
  int bm = blockIdx.y * 128, bn = blockIdx.x * 128;
  int wm = (wv >> 1) * 64, wn = (wv & 1) * 64;
  int m16 = lane & 15, q4 = lane >> 4;
  f32x4 zero4 = {0.f, 0.f, 0.f, 0.f};
  f32x4 acc[4][4];
#pragma unroll
  for (int mi = 0; mi < 4; ++mi)
#pragma unroll
    for (int ni = 0; ni < 4; ++ni) acc[mi][ni] = zero4;

  // staging: slot idx = c*256+tid; row=idx>>2, physblock=idx&3 holds logical
  // block (idx&3)^((idx>>3)&3). (idx>>3)&3 identical for both c halves.
  int r0 = tid >> 2;
  int c0 = (((tid & 3) ^ ((tid >> 3) & 3)) * 8);
  const bhalf* a0 = A + (size_t)(bm + r0) * K + c0;
  const bhalf* a1 = A + (size_t)(bm + 64 + r0) * K + c0;
  const bhalf* b0 = Bt + (size_t)(bn + r0) * K + c0;
  const bhalf* b1 = Bt + (size_t)(bn + 64 + r0) * K + c0;
  bhalf* lds_a0 = As + wv * 512;
  bhalf* lds_a1 = As + (4 + wv) * 512;
  bhalf* lds_b0 = Bs + wv * 512;
  bhalf* lds_b1 = Bs + (4 + wv) * 512;

  int swz = (m16 >> 1) & 3;  // (row>>1)&3 — row low bits come only from m16

  for (int k0 = 0; k0 < K; k0 += 32) {
    __builtin_amdgcn_global_load_lds((gas_p)(a0 + k0), (las_p)lds_a0, 16, 0, 0);
    __builtin_amdgcn_global_load_lds((gas_p)(a1 + k0), (las_p)lds_a1, 16, 0, 0);
    __builtin_amdgcn_global_load_lds((gas_p)(b0 + k0), (las_p)lds_b0, 16, 0, 0);
    __builtin_amdgcn_global_load_lds((gas_p)(b1 + k0), (las_p)lds_b1, 16, 0, 0);
    __syncthreads();
    bhalf8 af[4], bfr[4];
#pragma unroll
    for (int mi = 0; mi < 4; ++mi)
      af[mi] = *(const bhalf8*)&As[(wm + mi * 16 + m16) * 32 + ((q4 ^ swz) * 8)];
#pragma unroll
    for (int ni = 0; ni < 4; ++ni)
      bfr[ni] = *(const bhalf8*)&Bs[(wn + ni * 16 + m16) * 32 + ((q4 ^ swz) * 8)];
#pragma unroll
    for (int mi = 0; mi < 4; ++mi)
#pragma unroll
      for (int ni = 0; ni < 4; ++ni)
        acc[mi][ni] = __builtin_amdgcn_mfma_f32_16x16x32_bf16(af[mi], bfr[ni], acc[mi][ni], 0, 0, 0);
    __syncthreads();
  }
#pragma unroll
  for (int mi = 0; mi < 4; ++mi)
#pragma unroll
    for (int ni = 0; ni < 4; ++ni) {
      size_t base = (size_t)(bm + wm + mi * 16 + q4 * 4) * N + (bn + wn + ni * 16 + m16);
#pragma unroll
      for (int r = 0; r < 4; ++r) C[base + (size_t)r * N] = acc[mi][ni][r];
    }
}

// ---------------- fused RMSNorm + RoPE + split + cast ----------------
__global__ __launch_bounds__(256) void normrope_k(const float* __restrict__ qkv,
                                                  const int* __restrict__ pos,
                                                  const float* __restrict__ qw,
                                                  const float* __restrict__ kw,
                                                  bhalf* __restrict__ qo,
                                                  bhalf* __restrict__ ko,
                                                  bhalf* __restrict__ vo) {
  int wid = blockIdx.x * 4 + (threadIdx.x >> 6);
  int lane = threadIdx.x & 63;
  int t = wid / 48, h = wid - t * 48;
  float x = qkv[(size_t)t * NQKV + h * 64 + lane];
  float o = x;
  if (h < 40) {
    float ss = x * x;
#pragma unroll
    for (int off = 32; off; off >>= 1) ss += __shfl_xor(ss, off);
    float y = x * rsqrtf(ss * (1.0f / 64.0f) + 1e-5f) * ((h < 32) ? qw[lane] : kw[lane]);
    int i = lane & 31;
    float freq = exp2f((float)i * -0.6228615177913804f);
    float ang = (float)pos[t] * freq;
    float c = cosf(ang), s = sinf(ang);
    float partner = __shfl_xor(y, 32);
    o = (lane < 32) ? (y * c - partner * s) : (y * c + partner * s);
  }
  if (h < 32)      qo[(size_t)t * 2048 + h * 64 + lane] = (bhalf)o;
  else if (h < 40) ko[(size_t)t * 512 + (h - 32) * 64 + lane] = (bhalf)o;
  else             vo[(size_t)t * 512 + (h - 40) * 64 + lane] = (bhalf)o;
}

// ---------------- flash attention (causal GQA), throughput structure --------------
// grid (NQH, 16): block = (head, 128 q-rows); qt = 15 - blockIdx.y (heavy first).
// 4 waves; wave owns 32 q-rows (2 m-tiles). s-chunk = 64. K (64x64, [s][d]) and
// V^T (64x64, [d][s]) staged via global_load_lds into double-buffered LDS with
// XOR swizzle (src colblock = blk^(row&7)); one barrier per chunk, prefetch of
// chunk c+1 issued before compute of chunk c. Fixed-max softmax (|score|<=8).
__global__ __launch_bounds__(256) void attn_k(const bhalf* __restrict__ q,
                                              const bhalf* __restrict__ k,
                                              const bhalf* __restrict__ vt,
                                              bhalf* __restrict__ o) {
  __shared__ __align__(16) bhalf Kb[2][64 * 64];
  __shared__ __align__(16) bhalf Vb[2][64 * 64];
  __shared__ __align__(16) bhalf Pb[4][32][72];
  int tid = threadIdx.x, lane = tid & 63, w = tid >> 6;
  int h = blockIdx.x, kh = h >> 2;
  int qt = 15 - blockIdx.y;
  int qb = qt * 128;
  int m16 = lane & 15, q4 = lane >> 4;
  int nch = 2 * qt + 2;
  int wrow0 = qb + w * 32;
  int wave_tmax = wrow0 + 31;

  const float C1 = 0.18033688011112042f;  // 0.125 * log2(e)
  const float C2 = 11.541560327111707f;   // 8 * log2(e)

  // Q fragments (A-layout): row = wrow0 + mt*16 + m16, k = kq*32 + q4*8
  bhalf8 qf[2][2];
#pragma unroll
  for (int mt = 0; mt < 2; ++mt) {
    const bhalf* qp = q + (size_t)(wrow0 + mt * 16 + m16) * 2048 + h * 64;
#pragma unroll
    for (int kq = 0; kq < 2; ++kq) qf[mt][kq] = *(const bhalf8*)(qp + kq * 32 + q4 * 8);
  }

  // staging coords: thread covers LDS rows j*32 + (tid>>3), physblock tid&7,
  // which must hold global colblock (tid&7)^((tid>>3)&7).
  int srow = tid >> 3;
  int scol = (((tid & 7) ^ (srow & 7)) * 8);
  const bhalf* ksrc = k + (size_t)srow * 512 + kh * 64 + scol;
  const bhalf* vsrc = vt + (size_t)(kh * 64 + srow) * 2048 + scol;
  bhalf* kdst = &Kb[0][0] + w * 512;  // + buf*4096 + j*2048 (elements)
  bhalf* vdst = &Vb[0][0] + w * 512;

  auto stage = [&](int c) {
    int buf = c & 1, s0 = c * 64;
#pragma unroll
    for (int j = 0; j < 2; ++j) {
      __builtin_amdgcn_global_load_lds((gas_p)(ksrc + (size_t)(s0 + j * 32) * 512),
                                       (las_p)(kdst + buf * 4096 + j * 2048), 16, 0, 0);
      __builtin_amdgcn_global_load_lds((gas_p)(vsrc + (size_t)(j * 32) * 2048 + s0),
                                       (las_p)(vdst + buf * 4096 + j * 2048), 16, 0, 0);
    }
  };

  f32x4 zero4 = {0.f, 0.f, 0.f, 0.f};
  f32x4 oac[2][4];
  float psum[2][4];
#pragma unroll
  for (int mt = 0; mt < 2; ++mt)
#pragma unroll
    for (int ni = 0; ni < 4; ++ni) oac[mt][ni] = zero4;
#pragma unroll
  for (int mt = 0; mt < 2; ++mt)
#pragma unroll
    for (int r = 0; r < 4; ++r) psum[mt][r] = 0.f;

  int swz = m16 & 7;

  stage(0);
  for (int c = 0; c < nch; ++c) {
    __syncthreads();  // vmcnt(0) drain => buf c ready; prior reads of other buf done
    if (c + 1 < nch) stage(c + 1);
    int s0 = c * 64;
    if (s0 <= wave_tmax) {
      int buf = c & 1;
      int stmax = (wave_tmax >= s0 + 63) ? 3 : ((wave_tmax - s0) >> 4);
      int stwr = (stmax >= 2) ? 3 : 1;
      // K fragments (B-layout): n = st*16+m16 (s), k = ks*32+q4*8 (d)
      bhalf8 kf[4][2];
#pragma unroll
      for (int st = 0; st < 4; ++st)
        if (st <= stmax)
#pragma unroll
          for (int ks = 0; ks < 2; ++ks)
            kf[st][ks] = *(const bhalf8*)&Kb[buf][(st * 16 + m16) * 64 + (((ks * 4 + q4) ^ swz) * 8)];
      f32x4 sv[2][4];
#pragma unroll
      for (int mt = 0; mt < 2; ++mt)
#pragma unroll
        for (int st = 0; st < 4; ++st)
          if (st <= stmax) {
            f32x4 t0 = __builtin_amdgcn_mfma_f32_16x16x32_bf16(qf[mt][0], kf[st][0], zero4, 0, 0, 0);
            sv[mt][st] = __builtin_amdgcn_mfma_f32_16x16x32_bf16(qf[mt][1], kf[st][1], t0, 0, 0, 0);
          }
      // mask + exp + store P (C-layout row = q4*4+r, col = st*16+m16)
#pragma unroll
      for (int mt = 0; mt < 2; ++mt)
#pragma unroll
        for (int st = 0; st < 4; ++st) {
          if (st > stwr) continue;
#pragma unroll
          for (int r = 0; r < 4; ++r) {
            float pe = 0.f;
            if (st <= stmax) {
              int trow = wrow0 + mt * 16 + q4 * 4 + r;
              int col = s0 + st * 16 + m16;
              pe = (col <= trow) ? exp2f(sv[mt][st][r] * C1 - C2) : 0.f;
            }
            psum[mt][r] += pe;
            Pb[w][mt * 16 + q4 * 4 + r][st * 16 + m16] = (bhalf)pe;
          }
        }
      // PV: A = P from LDS, B = V^T fragments
      int ksmax = (stmax >= 2) ? 1 : 0;
      bhalf8 vf[4][2];
#pragma unroll
      for (int ni = 0; ni < 4; ++ni)
#pragma unroll
        for (int ks = 0; ks < 2; ++ks)
          if (ks <= ksmax)
            vf[ni][ks] = *(const bhalf8*)&Vb[buf][(ni * 16 + m16) * 64 + (((ks * 4 + q4) ^ swz) * 8)];
#pragma unroll
      for (int mt = 0; mt < 2; ++mt) {
        bhalf8 ap0 = *(const bhalf8*)&Pb[w][mt * 16 + m16][q4 * 8];
#pragma unroll
        for (int ni = 0; ni < 4; ++ni)
          oac[mt][ni] = __builtin_amdgcn_mfma_f32_16x16x32_bf16(ap0, vf[ni][0], oac[mt][ni], 0, 0, 0);
        if (ksmax) {
          bhalf8 ap1 = *(const bhalf8*)&Pb[w][mt * 16 + m16][32 + q4 * 8];
#pragma unroll
          for (int ni = 0; ni < 4; ++ni)
            oac[mt][ni] = __builtin_amdgcn_mfma_f32_16x16x32_bf16(ap1, vf[ni][1], oac[mt][ni], 0, 0, 0);
        }
      }
    }
  }
  // reduce psum across the 16 m16-lanes of each q4 group, then write O
#pragma unroll
  for (int mt = 0; mt < 2; ++mt)
#pragma unroll
    for (int r = 0; r < 4; ++r) {
      float ps = psum[mt][r];
      ps += __shfl_xor(ps, 1);
      ps += __shfl_xor(ps, 2);
      ps += __shfl_xor(ps, 4);
      ps += __shfl_xor(ps, 8);
      psum[mt][r] = 1.0f / ps;
    }
#pragma unroll
  for (int mt = 0; mt < 2; ++mt)
#pragma unroll
    for (int ni = 0; ni < 4; ++ni)
#pragma unroll
      for (int r = 0; r < 4; ++r) {
        int trow = wrow0 + mt * 16 + q4 * 4 + r;
        o[(size_t)trow * 2048 + h * 64 + ni * 16 + m16] = (bhalf)(oac[mt][ni][r] * psum[mt][r]);
      }
}

extern "C" void kernel_launch(void* const* d_in, const int* in_sizes, int n_in,
                              void* d_out, int out_size, void* d_ws, size_t ws_size,
                              hipStream_t stream) {
  const int* positions = (const int*)d_in[0];
  const float* hidden  = (const float*)d_in[1];
  const float* w_qkv   = (const float*)d_in[2];
  const float* w_out   = (const float*)d_in[3];
  const float* q_ln    = (const float*)d_in[4];
  const float* k_ln    = (const float*)d_in[5];
  float* out = (float*)d_out;

  char* wsp = (char*)d_ws;
  bhalf* hid_bf  = (bhalf*)(wsp);                 //  8,388,608 B (dead after gemm1)
  bhalf* wqkvT   = (bhalf*)(wsp + 8388608);       // 12,582,912 B (3072 x 2048)
  bhalf* woutT   = (bhalf*)(wsp + 20971520);      //  8,388,608 B (2048 x 2048)
  float* qkv     = (float*)(wsp + 29360128);      // 25,165,824 B (2048 x 3072 fp32)
  bhalf* q_bf    = (bhalf*)(wsp + 54525952);      //  8,388,608 B
  bhalf* k_bf    = (bhalf*)(wsp + 62914560);      //  2,097,152 B
  bhalf* v_bf    = (bhalf*)(wsp + 65011712);      //  2,097,152 B  (total 64 MiB)
  bhalf* vt_g    = (bhalf*)(wsp);                 // aliases hid_bf (dead by then)
  bhalf* attn_bf = (bhalf*)(wsp + 29360128);      // aliases qkv (dead after normrope)

  cast_bf16_k<<<T_SEQ * HIDN / 1024, 256, 0, stream>>>(hidden, hid_bf, T_SEQ * HIDN);
  transpose_cast_k<<<dim3(NQKV / 32, HIDN / 32), 256, 0, stream>>>(w_qkv, wqkvT, HIDN, NQKV);
  transpose_cast_k<<<dim3(HIDN / 32, HIDN / 32), 256, 0, stream>>>(w_out, woutT, HIDN, HIDN);
  gemm_bf16_k<<<dim3(NQKV / 128, T_SEQ / 128), 256, 0, stream>>>(hid_bf, wqkvT, qkv,
                                                                 T_SEQ, NQKV, HIDN);
  normrope_k<<<T_SEQ * 48 / 4, 256, 0, stream>>>(qkv, positions, q_ln, k_ln, q_bf, k_bf, v_bf);
  transpose_bf16_k<<<dim3(512 / 32, T_SEQ / 32), 256, 0, stream>>>(v_bf, vt_g, T_SEQ, 512);
  attn_k<<<dim3(NQH, 16), 256, 0, stream>>>(q_bf, k_bf, vt_g, attn_bf);
  gemm_bf16_k<<<dim3(HIDN / 128, T_SEQ / 128), 256, 0, stream>>>(attn_bf, woutT, out,
                                                                 T_SEQ, HIDN, HIDN);
}

// Round 4
// 222.681 us; speedup vs baseline: 2.0432x; 1.3444x over previous
//
#include <hip/hip_runtime.h>

typedef __bf16 bhalf;
typedef __bf16 bhalf8 __attribute__((ext_vector_type(8)));
typedef __bf16 bhalf4 __attribute__((ext_vector_type(4)));
typedef float f32x4 __attribute__((ext_vector_type(4)));

typedef __attribute__((address_space(1))) const void* gas_p;
typedef __attribute__((address_space(3))) void* las_p;

#define T_SEQ 2048
#define HIDN  2048
#define NQH   32
#define NKVH  8
#define DH    64
#define NQKV  3072

// ---------------- elementwise cast fp32 -> bf16 ----------------
__global__ __launch_bounds__(256) void cast_bf16_k(const float* __restrict__ in,
                                                   bhalf* __restrict__ out, int n) {
  int i = (blockIdx.x * 256 + threadIdx.x) * 4;
  if (i + 3 < n) {
    float4 v = *(const float4*)(in + i);
    bhalf4 o;
    o[0] = (bhalf)v.x; o[1] = (bhalf)v.y; o[2] = (bhalf)v.z; o[3] = (bhalf)v.w;
    *(bhalf4*)(out + i) = o;
  }
}

// ---------------- transpose + cast fp32->bf16: out[C][R] = (bf16) in[R][C] -------------
__global__ __launch_bounds__(256) void transpose_cast_k(const float* __restrict__ in,
                                                        bhalf* __restrict__ out, int R, int C) {
  __shared__ float tile[32][33];
  int bx = blockIdx.x * 32;
  int by = blockIdx.y * 32;
  int tx = threadIdx.x & 31, ty = threadIdx.x >> 5;
#pragma unroll
  for (int p = 0; p < 4; ++p)
    tile[ty + 8 * p][tx] = in[(size_t)(by + ty + 8 * p) * C + bx + tx];
  __syncthreads();
#pragma unroll
  for (int p = 0; p < 4; ++p)
    out[(size_t)(bx + ty + 8 * p) * R + by + tx] = (bhalf)tile[tx][ty + 8 * p];
}

// ---------------- bf16 transpose: out[C][R] = in[R][C] ----------------
__global__ __launch_bounds__(256) void transpose_bf16_k(const bhalf* __restrict__ in,
                                                        bhalf* __restrict__ out, int R, int C) {
  __shared__ bhalf tile[32][33];
  int bx = blockIdx.x * 32;
  int by = blockIdx.y * 32;
  int tx = threadIdx.x & 31, ty = threadIdx.x >> 5;
#pragma unroll
  for (int p = 0; p < 4; ++p)
    tile[ty + 8 * p][tx] = in[(size_t)(by + ty + 8 * p) * C + bx + tx];
  __syncthreads();
#pragma unroll
  for (int p = 0; p < 4; ++p)
    out[(size_t)(bx + ty + 8 * p) * R + by + tx] = tile[tx][ty + 8 * p];
}

// ---------------- shared GEMM core: 128(M) x 64(N) tile, BK=64 ----------------
// 4 waves stacked in M (wave tile 32x64). XOR-swizzled LDS staged via
// global_load_lds width=16. acc[mi(2)][ni(4)] of 16x16x32 bf16 MFMAs.
__device__ __forceinline__ void gemm_core(const bhalf* __restrict__ A,
                                          const bhalf* __restrict__ Bt, int K,
                                          int bm, int bn, int tid,
                                          bhalf* As, bhalf* Bs, f32x4 acc[2][4]) {
  int lane = tid & 63, wv = tid >> 6;
  int m16 = lane & 15, q4 = lane >> 4;
  int srow = tid >> 3;                         // 0..31
  int scol = ((tid & 7) ^ (srow & 7)) * 8;     // XOR-swizzled source col block
  const bhalf* asrc = A + (size_t)(bm + srow) * K + scol;
  const bhalf* bsrc = Bt + (size_t)(bn + srow) * K + scol;
  bhalf* adst = As + (wv * 8) * 64;
  bhalf* bdst = Bs + (wv * 8) * 64;
  int swz = m16 & 7;

  for (int k0 = 0; k0 < K; k0 += 64) {
#pragma unroll
    for (int c = 0; c < 4; ++c)
      __builtin_amdgcn_global_load_lds((gas_p)(asrc + (size_t)(c * 32) * K + k0),
                                       (las_p)(adst + c * 2048), 16, 0, 0);
#pragma unroll
    for (int c = 0; c < 2; ++c)
      __builtin_amdgcn_global_load_lds((gas_p)(bsrc + (size_t)(c * 32) * K + k0),
                                       (las_p)(bdst + c * 2048), 16, 0, 0);
    __syncthreads();
    bhalf8 af[2][2], bf[4][2];
#pragma unroll
    for (int mi = 0; mi < 2; ++mi)
#pragma unroll
      for (int ks = 0; ks < 2; ++ks)
        af[mi][ks] = *(const bhalf8*)&As[(wv * 32 + mi * 16 + m16) * 64 +
                                         (((ks * 4 + q4) ^ swz) * 8)];
#pragma unroll
    for (int ni = 0; ni < 4; ++ni)
#pragma unroll
      for (int ks = 0; ks < 2; ++ks)
        bf[ni][ks] = *(const bhalf8*)&Bs[(ni * 16 + m16) * 64 +
                                         (((ks * 4 + q4) ^ swz) * 8)];
#pragma unroll
    for (int mi = 0; mi < 2; ++mi)
#pragma unroll
      for (int ni = 0; ni < 4; ++ni) {
        acc[mi][ni] = __builtin_amdgcn_mfma_f32_16x16x32_bf16(af[mi][0], bf[ni][0], acc[mi][ni], 0, 0, 0);
        acc[mi][ni] = __builtin_amdgcn_mfma_f32_16x16x32_bf16(af[mi][1], bf[ni][1], acc[mi][ni], 0, 0, 0);
      }
    __syncthreads();
  }
}

// ---------------- GEMM1 + fused RMSNorm + RoPE + split + cast ----------------
// N-tile 64 == one head (h = blockIdx.x: 0..31 q, 32..39 k, 40..47 v).
__global__ __launch_bounds__(256) void gemm1_fused_k(const bhalf* __restrict__ A,
                                                     const bhalf* __restrict__ Bt,
                                                     const int* __restrict__ pos,
                                                     const float* __restrict__ qw,
                                                     const float* __restrict__ kw,
                                                     bhalf* __restrict__ qo,
                                                     bhalf* __restrict__ ko,
                                                     bhalf* __restrict__ vo) {
  __shared__ __align__(16) bhalf As[128 * 64];
  __shared__ __align__(16) bhalf Bs[64 * 64];
  int tid = threadIdx.x, lane = tid & 63, wv = tid >> 6;
  int m16 = lane & 15, q4 = lane >> 4;
  int bm = blockIdx.y * 128, bn = blockIdx.x * 64, h = blockIdx.x;
  f32x4 zero4 = {0.f, 0.f, 0.f, 0.f};
  f32x4 acc[2][4];
#pragma unroll
  for (int mi = 0; mi < 2; ++mi)
#pragma unroll
    for (int ni = 0; ni < 4; ++ni) acc[mi][ni] = zero4;

  gemm_core(A, Bt, HIDN, bm, bn, tid, As, Bs, acc);

  int wr0 = wv * 32;
  if (h < 40) {
    float wd[4];
    const float* wptr = (h < 32) ? qw : kw;
#pragma unroll
    for (int ni = 0; ni < 4; ++ni) wd[ni] = wptr[ni * 16 + m16];
    float f0 = exp2f((float)m16 * -0.6228615177913804f);
    float f1 = f0 * 0.001f;  // theta^(-16/32) = 1e-3
#pragma unroll
    for (int mi = 0; mi < 2; ++mi)
#pragma unroll
      for (int r = 0; r < 4; ++r) {
        int trow = bm + wr0 + mi * 16 + q4 * 4 + r;
        float x0 = acc[mi][0][r], x1 = acc[mi][1][r], x2 = acc[mi][2][r], x3 = acc[mi][3][r];
        float ss = x0 * x0 + x1 * x1 + x2 * x2 + x3 * x3;
        ss += __shfl_xor(ss, 1);
        ss += __shfl_xor(ss, 2);
        ss += __shfl_xor(ss, 4);
        ss += __shfl_xor(ss, 8);
        float sc = rsqrtf(ss * (1.0f / 64.0f) + 1e-5f);
        float y0 = x0 * sc * wd[0], y1 = x1 * sc * wd[1];
        float y2 = x2 * sc * wd[2], y3 = x3 * sc * wd[3];
        float p = (float)pos[trow];
        float a0 = p * f0, a1 = p * f1;
        float c0 = cosf(a0), s0 = sinf(a0), c1 = cosf(a1), s1 = sinf(a1);
        float o0 = y0 * c0 - y2 * s0, o2 = y2 * c0 + y0 * s0;
        float o1 = y1 * c1 - y3 * s1, o3 = y3 * c1 + y1 * s1;
        bhalf* dst = (h < 32) ? (qo + (size_t)trow * 2048 + h * 64 + m16)
                              : (ko + (size_t)trow * 512 + (h - 32) * 64 + m16);
        dst[0] = (bhalf)o0; dst[16] = (bhalf)o1; dst[32] = (bhalf)o2; dst[48] = (bhalf)o3;
      }
  } else {
#pragma unroll
    for (int mi = 0; mi < 2; ++mi)
#pragma unroll
      for (int r = 0; r < 4; ++r) {
        int trow = bm + wr0 + mi * 16 + q4 * 4 + r;
        bhalf* dst = vo + (size_t)trow * 512 + (h - 40) * 64 + m16;
        dst[0] = (bhalf)acc[mi][0][r]; dst[16] = (bhalf)acc[mi][1][r];
        dst[32] = (bhalf)acc[mi][2][r]; dst[48] = (bhalf)acc[mi][3][r];
      }
  }
}

// ---------------- GEMM2: plain fp32-out epilogue ----------------
__global__ __launch_bounds__(256) void gemm2_k(const bhalf* __restrict__ A,
                                               const bhalf* __restrict__ Bt,
                                               float* __restrict__ C) {
  __shared__ __align__(16) bhalf As[128 * 64];
  __shared__ __align__(16) bhalf Bs[64 * 64];
  int tid = threadIdx.x, lane = tid & 63, wv = tid >> 6;
  int m16 = lane & 15, q4 = lane >> 4;
  int bm = blockIdx.y * 128, bn = blockIdx.x * 64;
  f32x4 zero4 = {0.f, 0.f, 0.f, 0.f};
  f32x4 acc[2][4];
#pragma unroll
  for (int mi = 0; mi < 2; ++mi)
#pragma unroll
    for (int ni = 0; ni < 4; ++ni) acc[mi][ni] = zero4;

  gemm_core(A, Bt, HIDN, bm, bn, tid, As, Bs, acc);

  int wr0 = wv * 32;
#pragma unroll
  for (int mi = 0; mi < 2; ++mi)
#pragma unroll
    for (int r = 0; r < 4; ++r) {
      size_t base = (size_t)(bm + wr0 + mi * 16 + q4 * 4 + r) * 2048 + bn + m16;
      C[base] = acc[mi][0][r]; C[base + 16] = acc[mi][1][r];
      C[base + 32] = acc[mi][2][r]; C[base + 48] = acc[mi][3][r];
    }
}

// ---------------- flash attention (causal GQA), fixed-max softmax ----------------
// grid (NQH, 32): block = (head, 64 q-rows), qt = 31 - by (heavy first).
// 4 waves; wave owns 16 q-rows. s-chunk 64, K/V^T double-buffered via
// global_load_lds + XOR swizzle, 1 barrier/chunk. Interior chunks take an
// unmasked fast path; only the diagonal chunk (c==qt) masks.
__global__ __launch_bounds__(256) void attn_k(const bhalf* __restrict__ q,
                                              const bhalf* __restrict__ k,
                                              const bhalf* __restrict__ vt,
                                              bhalf* __restrict__ o) {
  __shared__ __align__(16) bhalf Kb[2][4096];
  __shared__ __align__(16) bhalf Vb[2][4096];
  __shared__ __align__(16) bhalf Pb[4][16][72];
  int tid = threadIdx.x, lane = tid & 63, w = tid >> 6;
  int h = blockIdx.x, kh = h >> 2;
  int qt = 31 - blockIdx.y;
  int qb = qt * 64;
  int m16 = lane & 15, q4 = lane >> 4;
  int wrow0 = qb + w * 16;

  const float C1 = 0.18033688011112042f;  // 0.125 * log2(e)
  const float C2 = 11.541560327111707f;   // 8 * log2(e)

  const bhalf* qp = q + (size_t)(wrow0 + m16) * 2048 + h * 64;
  bhalf8 qf0 = *(const bhalf8*)(qp + q4 * 8);
  bhalf8 qf1 = *(const bhalf8*)(qp + 32 + q4 * 8);

  int srow = tid >> 3;
  int scol = ((tid & 7) ^ (srow & 7)) * 8;
  const bhalf* ksrc = k + (size_t)srow * 512 + kh * 64 + scol;
  const bhalf* vsrc = vt + (size_t)(kh * 64 + srow) * 2048 + scol;
  bhalf* kdst = &Kb[0][0] + w * 512;
  bhalf* vdst = &Vb[0][0] + w * 512;

  auto stage = [&](int c) {
    int buf = c & 1, s0 = c * 64;
#pragma unroll
    for (int j = 0; j < 2; ++j) {
      __builtin_amdgcn_global_load_lds((gas_p)(ksrc + (size_t)(s0 + j * 32) * 512),
                                       (las_p)(kdst + buf * 4096 + j * 2048), 16, 0, 0);
      __builtin_amdgcn_global_load_lds((gas_p)(vsrc + (size_t)(j * 32) * 2048 + s0),
                                       (las_p)(vdst + buf * 4096 + j * 2048), 16, 0, 0);
    }
  };

  f32x4 zero4 = {0.f, 0.f, 0.f, 0.f};
  f32x4 oac[4];
  float psum[4] = {0.f, 0.f, 0.f, 0.f};
#pragma unroll
  for (int ni = 0; ni < 4; ++ni) oac[ni] = zero4;
  int swz = m16 & 7;

  stage(0);
  for (int c = 0; c <= qt; ++c) {
    __syncthreads();  // implicit vmcnt(0) drain: buf c ready, prior buf reads done
    if (c < qt) stage(c + 1);
    int buf = c & 1, s0 = c * 64;
    if (c < qt) {
      // -------- interior chunk: fully unmasked --------
      bhalf8 kf[4][2];
#pragma unroll
      for (int st = 0; st < 4; ++st)
#pragma unroll
        for (int ks = 0; ks < 2; ++ks)
          kf[st][ks] = *(const bhalf8*)&Kb[buf][(st * 16 + m16) * 64 + (((ks * 4 + q4) ^ swz) * 8)];
      f32x4 sv[4];
#pragma unroll
      for (int st = 0; st < 4; ++st) {
        f32x4 t0 = __builtin_amdgcn_mfma_f32_16x16x32_bf16(qf0, kf[st][0], zero4, 0, 0, 0);
        sv[st] = __builtin_amdgcn_mfma_f32_16x16x32_bf16(qf1, kf[st][1], t0, 0, 0, 0);
      }
#pragma unroll
      for (int st = 0; st < 4; ++st)
#pragma unroll
        for (int r = 0; r < 4; ++r) {
          float pe = exp2f(sv[st][r] * C1 - C2);
          psum[r] += pe;
          Pb[w][q4 * 4 + r][st * 16 + m16] = (bhalf)pe;
        }
      bhalf8 vf[4][2];
#pragma unroll
      for (int ni = 0; ni < 4; ++ni)
#pragma unroll
        for (int ks = 0; ks < 2; ++ks)
          vf[ni][ks] = *(const bhalf8*)&Vb[buf][(ni * 16 + m16) * 64 + (((ks * 4 + q4) ^ swz) * 8)];
      bhalf8 ap0 = *(const bhalf8*)&Pb[w][m16][q4 * 8];
      bhalf8 ap1 = *(const bhalf8*)&Pb[w][m16][32 + q4 * 8];
#pragma unroll
      for (int ni = 0; ni < 4; ++ni) {
        oac[ni] = __builtin_amdgcn_mfma_f32_16x16x32_bf16(ap0, vf[ni][0], oac[ni], 0, 0, 0);
        oac[ni] = __builtin_amdgcn_mfma_f32_16x16x32_bf16(ap1, vf[ni][1], oac[ni], 0, 0, 0);
      }
    } else {
      // -------- diagonal chunk: wave w needs st 0..w --------
      bhalf8 kf[4][2];
      f32x4 sv[4];
#pragma unroll
      for (int st = 0; st < 4; ++st)
        if (st <= w) {
#pragma unroll
          for (int ks = 0; ks < 2; ++ks)
            kf[st][ks] = *(const bhalf8*)&Kb[buf][(st * 16 + m16) * 64 + (((ks * 4 + q4) ^ swz) * 8)];
          f32x4 t0 = __builtin_amdgcn_mfma_f32_16x16x32_bf16(qf0, kf[st][0], zero4, 0, 0, 0);
          sv[st] = __builtin_amdgcn_mfma_f32_16x16x32_bf16(qf1, kf[st][1], t0, 0, 0, 0);
        }
      int stwr = (w >= 2) ? 3 : 1;
#pragma unroll
      for (int st = 0; st < 4; ++st) {
        if (st > stwr) continue;
#pragma unroll
        for (int r = 0; r < 4; ++r) {
          float pe = 0.f;
          if (st <= w) {
            int trow = wrow0 + q4 * 4 + r;
            int col = s0 + st * 16 + m16;
            pe = (col <= trow) ? exp2f(sv[st][r] * C1 - C2) : 0.f;
          }
          psum[r] += pe;
          Pb[w][q4 * 4 + r][st * 16 + m16] = (bhalf)pe;
        }
      }
      int ksmax = (w >= 2) ? 1 : 0;
      bhalf8 vf[4][2];
#pragma unroll
      for (int ni = 0; ni < 4; ++ni)
#pragma unroll
        for (int ks = 0; ks < 2; ++ks)
          if (ks <= ksmax)
            vf[ni][ks] = *(const bhalf8*)&Vb[buf][(ni * 16 + m16) * 64 + (((ks * 4 + q4) ^ swz) * 8)];
      bhalf8 ap0 = *(const bhalf8*)&Pb[w][m16][q4 * 8];
#pragma unroll
      for (int ni = 0; ni < 4; ++ni)
        oac[ni] = __builtin_amdgcn_mfma_f32_16x16x32_bf16(ap0, vf[ni][0], oac[ni], 0, 0, 0);
      if (ksmax) {
        bhalf8 ap1 = *(const bhalf8*)&Pb[w][m16][32 + q4 * 8];
#pragma unroll
        for (int ni = 0; ni < 4; ++ni)
          oac[ni] = __builtin_amdgcn_mfma_f32_16x16x32_bf16(ap1, vf[ni][1], oac[ni], 0, 0, 0);
      }
    }
  }
#pragma unroll
  for (int r = 0; r < 4; ++r) {
    float ps = psum[r];
    ps += __shfl_xor(ps, 1);
    ps += __shfl_xor(ps, 2);
    ps += __shfl_xor(ps, 4);
    ps += __shfl_xor(ps, 8);
    psum[r] = 1.0f / ps;
  }
#pragma unroll
  for (int ni = 0; ni < 4; ++ni)
#pragma unroll
    for (int r = 0; r < 4; ++r) {
      int trow = wrow0 + q4 * 4 + r;
      o[(size_t)trow * 2048 + h * 64 + ni * 16 + m16] = (bhalf)(oac[ni][r] * psum[r]);
    }
}

extern "C" void kernel_launch(void* const* d_in, const int* in_sizes, int n_in,
                              void* d_out, int out_size, void* d_ws, size_t ws_size,
                              hipStream_t stream) {
  const int* positions = (const int*)d_in[0];
  const float* hidden  = (const float*)d_in[1];
  const float* w_qkv   = (const float*)d_in[2];
  const float* w_out   = (const float*)d_in[3];
  const float* q_ln    = (const float*)d_in[4];
  const float* k_ln    = (const float*)d_in[5];
  float* out = (float*)d_out;

  char* wsp = (char*)d_ws;
  bhalf* hid_bf  = (bhalf*)(wsp);                 //  8,388,608 B
  bhalf* wqkvT   = (bhalf*)(wsp + 8388608);       // 12,582,912 B (3072 x 2048)
  bhalf* woutT   = (bhalf*)(wsp + 20971520);      //  8,388,608 B (2048 x 2048)
  bhalf* q_bf    = (bhalf*)(wsp + 29360128);      //  8,388,608 B
  bhalf* k_bf    = (bhalf*)(wsp + 37748736);      //  2,097,152 B
  bhalf* v_bf    = (bhalf*)(wsp + 39845888);      //  2,097,152 B
  bhalf* vt_g    = (bhalf*)(wsp + 41943040);      //  2,097,152 B
  bhalf* attn_bf = (bhalf*)(wsp + 44040192);      //  8,388,608 B (ends 52.4 MB)

  cast_bf16_k<<<T_SEQ * HIDN / 1024, 256, 0, stream>>>(hidden, hid_bf, T_SEQ * HIDN);
  transpose_cast_k<<<dim3(NQKV / 32, HIDN / 32), 256, 0, stream>>>(w_qkv, wqkvT, HIDN, NQKV);
  transpose_cast_k<<<dim3(HIDN / 32, HIDN / 32), 256, 0, stream>>>(w_out, woutT, HIDN, HIDN);
  gemm1_fused_k<<<dim3(NQKV / 64, T_SEQ / 128), 256, 0, stream>>>(
      hid_bf, wqkvT, positions, q_ln, k_ln, q_bf, k_bf, v_bf);
  transpose_bf16_k<<<dim3(512 / 32, T_SEQ / 32), 256, 0, stream>>>(v_bf, vt_g, T_SEQ, 512);
  attn_k<<<dim3(NQH, 32), 256, 0, stream>>>(q_bf, k_bf, vt_g, attn_bf);
  gemm2_k<<<dim3(HIDN / 64, T_SEQ / 128), 256, 0, stream>>>(attn_bf, woutT, out);
}